// Round 4
// baseline (2928.261 us; speedup 1.0000x reference)
//
#include <hip/hip_runtime.h>

#define NDRUG 2528   // 32*79
#define NPROT 6144   // 32*192
#define NTOT  8672
#define EDRUG 5120
#define EPROT 12800
#define ETOT  17920
#define SEIN  15168
#define SEHID 2000
#define NSPLIT 16
#define NTOTF (NTOT*128)     // 1,110,016
#define GRID  512
#define BLK   256

// ---- software grid barrier (plain launches; graph-capture safe) ---------------
// Monotonic counter, no reset -> no reset race. Zeroed by hipMemsetAsync each
// launch. Residency guaranteed: launch_bounds(256,2) -> 2 blocks/CU x 256 CU
// = 512 = GRID for both kernels.
__device__ __forceinline__ void gbar(int* cnt, int target) {
    __threadfence();                       // agent-scope release of this block's writes
    __syncthreads();
    if (threadIdx.x == 0) {
        __hip_atomic_fetch_add(cnt, 1, __ATOMIC_ACQ_REL, __HIP_MEMORY_SCOPE_AGENT);
        while (__hip_atomic_load(cnt, __ATOMIC_ACQUIRE, __HIP_MEMORY_SCOPE_AGENT) < target)
            __builtin_amdgcn_s_sleep(8);
    }
    __syncthreads();
    __threadfence();                       // acquire side for all lanes
}

struct FrontArgs {
    const float *x1,*x2,*w1,*b1,*w2,*b2,*gw,*gas,*gad,*gb,*se1w,*se1b;
    const int *de,*pe;
    float *xA,*xB,*hbuf,*xsum,*asn,*adn,*sl,*WR1,*WC1,*cmidT;
    int *deg,*fill,*off,*eidx;
    int *bar;
};

struct TailArgs {
    const float *cmidT,*se2w,*se2b,*inter,*xsum;
    const float *fc1w,*fc1b,*fc2w,*fc2b,*fc3w,*fc3b,*fc4w,*fc4b,*outw,*outb;
    float *part,*wgt,*wr,*wc,*xx,*r1,*r2,*r3,*r4,*out;
    int *bar;
};

// ---- se1w row-reduction work unit: WR1[i,k] = sum_j W[(i*192+j)*2000+k] -------
__device__ __forceinline__ void stream_wr1(const float* __restrict__ W,
                                           float* __restrict__ WR1, int u, int tid) {
    if (u >= 79 * 8) return;
    int i = u >> 3, k = (u & 7) * 256 + tid;
    if (k >= SEHID) return;
    const float* p = W + (size_t)i * 192 * SEHID + k;
    float a0 = 0.f, a1 = 0.f, a2 = 0.f, a3 = 0.f;
    for (int jj = 0; jj < 192; jj += 4) {
        a0 += p[0]; a1 += p[SEHID]; a2 += p[2 * SEHID]; a3 += p[3 * SEHID];
        p += (size_t)4 * SEHID;
    }
    WR1[i * SEHID + k] = (a0 + a1) + (a2 + a3);
}

// ---- se1w col-reduction work unit: WC1[j,k] = sum_i W[(i*192+j)*2000+k] -------
__device__ __forceinline__ void stream_wc1(const float* __restrict__ W,
                                           float* __restrict__ WC1, int u, int tid) {
    if (u >= 192 * 8) return;
    int jr = u >> 3, k = (u & 7) * 256 + tid;
    if (k >= SEHID) return;
    const float* p = W + (size_t)jr * SEHID + k;
    const size_t st = (size_t)192 * SEHID;
    float a0 = 0.f, a1 = 0.f, a2 = 0.f, a3 = 0.f;
    for (int i = 0; i < 76; i += 4) {
        a0 += p[0]; a1 += p[st]; a2 += p[2 * st]; a3 += p[3 * st];
        p += 4 * st;
    }
    a0 += p[0]; a1 += p[st]; a2 += p[2 * st];   // i = 76,77,78
    WC1[jr * SEHID + k] = (a0 + a1) + (a2 + a3);
}

// ---- 16-row x 128-col GEMM tile, executed by a 128-thread unit ----------------
__device__ __forceinline__ void gemm_tile(const float* __restrict__ A1,
                                          const float* __restrict__ A2, int K,
                                          const float* __restrict__ B,
                                          const float* __restrict__ bias,
                                          float* __restrict__ C,
                                          int tile, bool ok, int j, float* al) {
    __syncthreads();
    if (ok) {
        int r0 = tile * 16;
        const float* A = (A2 && r0 >= NDRUG) ? (A2 + (size_t)(r0 - NDRUG) * K)
                                             : (A1 + (size_t)r0 * K);
        for (int idx = j; idx < 16 * K; idx += 128) al[idx] = A[idx];
    }
    __syncthreads();
    if (ok) {
        int r0 = tile * 16;
        float acc[16];
#pragma unroll
        for (int r = 0; r < 16; r++) acc[r] = 0.f;
        for (int k = 0; k < K; k++) {
            float bv = B[k * 128 + j];
#pragma unroll
            for (int r = 0; r < 16; r++) acc[r] += al[r * K + k] * bv;
        }
        float bb = bias[j];
#pragma unroll
        for (int r = 0; r < 16; r++)
            C[(size_t)(r0 + r) * 128 + j] = fmaxf(acc[r] + bb, 0.f);
    }
}

// ---- GAT h = X@W + per-node as/ad, one 16-row tile per 128-thread unit --------
__device__ __forceinline__ void gat_tile(const FrontArgs& a, const float* __restrict__ X,
                                         int l, int tile, bool ok, int j,
                                         float* al, float (*hl)[129]) {
    __syncthreads();
    if (ok) {
        int r0 = tile * 16;
        for (int idx = j; idx < 2048; idx += 128) al[idx] = X[(size_t)r0 * 128 + idx];
    }
    __syncthreads();
    int li = (tile < 158) ? l : l + 3;
    const float* Wm = a.gw + (size_t)li * 16384;
    if (ok) {
        int r0 = tile * 16;
        float acc[16];
#pragma unroll
        for (int r = 0; r < 16; r++) acc[r] = 0.f;
        for (int k = 0; k < 128; k++) {
            float bv = Wm[k * 128 + j];
#pragma unroll
            for (int r = 0; r < 16; r++) acc[r] += al[r * 128 + k] * bv;
        }
#pragma unroll
        for (int r = 0; r < 16; r++) {
            a.hbuf[(size_t)(r0 + r) * 128 + j] = acc[r];
            hl[r][j] = acc[r];
        }
    }
    __syncthreads();
    if (ok) {
        int r0 = tile * 16;
        const float* avs = a.gas + li * 128;
        const float* avd = a.gad + li * 128;
        int r = j >> 3, l8 = j & 7;
        float ps = 0.f, pd = 0.f;
        for (int jj = l8; jj < 128; jj += 8) {
            float v = hl[r][jj];
            ps += v * avs[jj];
            pd += v * avd[jj];
        }
        ps += __shfl_down(ps, 4); ps += __shfl_down(ps, 2); ps += __shfl_down(ps, 1);
        pd += __shfl_down(pd, 4); pd += __shfl_down(pd, 2); pd += __shfl_down(pd, 1);
        if (l8 == 0) { a.asn[r0 + r] = ps; a.adn[r0 + r] = pd; }
    }
}

// ---- GAT gather for one (node,feature) ----------------------------------------
__device__ __forceinline__ float gather_one(const FrontArgs& a, int gid, int l) {
    int i = gid >> 7, f = gid & 127;
    float adi = a.adn[i];
    float ev = a.asn[i] + adi;
    ev = (ev > 0.f) ? ev : 0.2f * ev;
    float w = __expf(ev);
    float acc = w * a.hbuf[(size_t)i * 128 + f];
    float den = w;
    int e0 = a.off[i], e1 = a.off[i + 1];
    for (int e = e0; e < e1; e++) {
        int s = a.eidx[e];
        float es = a.asn[s] + adi;
        es = (es > 0.f) ? es : 0.2f * es;
        float we = __expf(es);
        acc += we * a.hbuf[(size_t)s * 128 + f];
        den += we;
    }
    const float* bv = (i < NDRUG) ? (a.gb + l * 128) : (a.gb + (l + 3) * 128);
    return fmaxf(acc / den + bv[f], 0.f);
}

// =============================== FRONT =========================================
// 512 blocks x 256. Even blocks = chain (CSR, MLP, GAT); odd = se1w streaming.
__global__ __launch_bounds__(BLK, 2) void front(FrontArgs a) {
    const int gbid = blockIdx.x;
    const int tid  = threadIdx.x;
    const bool chain = (gbid & 1) == 0;
    const int hbid = gbid >> 1;          // 0..255 within role
    const int uh = tid >> 7;             // 128-thread unit 0/1
    const int j  = tid & 127;
    int bt = 0;

    __shared__ float shf[2][2048 + 16 * 129];
    __shared__ int   s_scan[256];
    __shared__ float s_red[4];
    float* al = shf[uh];
    float (*hl)[129] = (float(*)[129])(shf[uh] + 2048);

    // ---- P0: zero deg/fill | stream wr1k slice 0
    if (chain) {
        int idx = hbid * 256 + tid;
        if (idx < NTOT) { a.deg[idx] = 0; a.fill[idx] = 0; }
    } else stream_wr1(a.se1w, a.WR1, 0 * 256 + hbid, tid);
    bt += GRID; gbar(a.bar, bt);

    // ---- P1: edge count + node-MLP layer1 (K=52) | wr1k slice 1
    if (chain) {
        if (hbid < 16) {
            for (int e = hbid * 256 + tid; e < ETOT; e += 4096) {
                int d;
                if (e < EDRUG) d = a.de[EDRUG + e];
                else d = a.pe[EPROT + (e - EDRUG)] + NDRUG;
                atomicAdd(&a.deg[d], 1);
            }
        } else {
            int unit = (hbid - 16) * 2 + uh;        // 0..479
            for (int rep = 0; rep < 2; rep++) {
                int tile = unit + rep * 480;
                gemm_tile(a.x1, a.x2, 52, a.w1, a.b1, a.xB, tile, tile < 542, j, al);
            }
        }
    } else stream_wr1(a.se1w, a.WR1, 1 * 256 + hbid, tid);
    bt += GRID; gbar(a.bar, bt);

    // ---- P2: CSR scan (block 0) + node-MLP layer2 (K=128) | wr1k slice 2
    if (chain) {
        if (hbid == 0) {
            const int per = 34;                     // 34*256 >= NTOT
            int s = 0;
            for (int c = 0; c < per; c++) {
                int idx = tid * per + c;
                if (idx < NTOT) s += a.deg[idx];
            }
            s_scan[tid] = s;
            __syncthreads();
            for (int d = 1; d < 256; d <<= 1) {
                int v = (tid >= d) ? s_scan[tid - d] : 0;
                __syncthreads();
                s_scan[tid] += v;
                __syncthreads();
            }
            int run = (tid == 0) ? 0 : s_scan[tid - 1];
            for (int c = 0; c < per; c++) {
                int idx = tid * per + c;
                if (idx < NTOT) { a.off[idx] = run; run += a.deg[idx]; }
            }
            if (tid == 255) a.off[NTOT] = run;
        } else {
            int unit = (hbid - 1) * 2 + uh;         // 0..509
            for (int rep = 0; rep < 2; rep++) {
                int tile = unit + rep * 510;
                gemm_tile(a.xB, nullptr, 128, a.w2, a.b2, a.xA, tile, tile < 542, j, al);
            }
        }
    } else stream_wr1(a.se1w, a.WR1, 2 * 256 + hbid, tid);
    bt += GRID; gbar(a.bar, bt);

    // ---- P3: CSR fill + gat_h L0 | wc1k slice 0
    if (chain) {
        if (hbid < 16) {
            for (int e = hbid * 256 + tid; e < ETOT; e += 4096) {
                int s, d;
                if (e < EDRUG) { s = a.de[e]; d = a.de[EDRUG + e]; }
                else { int ep = e - EDRUG; s = a.pe[ep] + NDRUG; d = a.pe[EPROT + ep] + NDRUG; }
                int pos = a.off[d] + atomicAdd(&a.fill[d], 1);
                a.eidx[pos] = s;
            }
        } else {
            int unit = (hbid - 16) * 2 + uh;
            for (int rep = 0; rep < 2; rep++) {
                int tile = unit + rep * 480;
                gat_tile(a, a.xA, 0, tile, tile < 542, j, al, hl);
            }
        }
    } else stream_wc1(a.se1w, a.WC1, 0 * 256 + hbid, tid);
    bt += GRID; gbar(a.bar, bt);

    // ---- P4: gather L0 -> xB, xsum=val | wc1k slice 1
    if (chain) {
        for (int it = 0; it < 17; it++) {
            int gid = it * 65536 + hbid * 256 + tid;
            if (gid < NTOTF) {
                float v = gather_one(a, gid, 0);
                a.xB[gid] = v;
                a.xsum[gid] = v;
            }
        }
    } else stream_wc1(a.se1w, a.WC1, 1 * 256 + hbid, tid);
    bt += GRID; gbar(a.bar, bt);

    // ---- P5: gat_h L1 | wc1k slice 2
    if (chain) {
        if (hbid >= 16) {
            int unit = (hbid - 16) * 2 + uh;
            for (int rep = 0; rep < 2; rep++) {
                int tile = unit + rep * 480;
                gat_tile(a, a.xB, 1, tile, tile < 542, j, al, hl);
            }
        }
    } else stream_wc1(a.se1w, a.WC1, 2 * 256 + hbid, tid);
    bt += GRID; gbar(a.bar, bt);

    // ---- P6: gather L1 -> xA, xsum+= | wc1k slice 3
    if (chain) {
        for (int it = 0; it < 17; it++) {
            int gid = it * 65536 + hbid * 256 + tid;
            if (gid < NTOTF) {
                float v = gather_one(a, gid, 1);
                a.xA[gid] = v;
                a.xsum[gid] += v;
            }
        }
    } else stream_wc1(a.se1w, a.WC1, 3 * 256 + hbid, tid);
    bt += GRID; gbar(a.bar, bt);

    // ---- P7: gat_h L2 | wc1k slice 4
    if (chain) {
        int unit = hbid * 2 + uh;                   // 0..511
        for (int rep = 0; rep < 2; rep++) {
            int tile = unit + rep * 512;
            gat_tile(a, a.xA, 2, tile, tile < 542, j, al, hl);
        }
    } else stream_wc1(a.se1w, a.WC1, 4 * 256 + hbid, tid);
    bt += GRID; gbar(a.bar, bt);

    // ---- P8: gather L2 + xsum += + fused per-node rowsum | wc1k slice 5
    if (chain) {
        for (int it = 0; it < 17; it++) {
            int base = (it * 256 + hbid) * 256;     // block-contiguous 256 gids
            int gid = base + tid;
            bool live = gid < NTOTF;
            float xs = 0.f;
            if (live) {
                float v = gather_one(a, gid, 2);
                xs = a.xsum[gid] + v;
                a.xsum[gid] = xs;
            }
            float rv = live ? xs : 0.f;
            rv += __shfl_down(rv, 32); rv += __shfl_down(rv, 16); rv += __shfl_down(rv, 8);
            rv += __shfl_down(rv, 4);  rv += __shfl_down(rv, 2);  rv += __shfl_down(rv, 1);
            if ((tid & 63) == 0) s_red[tid >> 6] = rv;
            __syncthreads();
            if (tid == 0) {
                int nA = (it * 256 + hbid) * 2;
                if (nA < NTOT)     a.sl[nA]     = s_red[0] + s_red[1];
                if (nA + 1 < NTOT) a.sl[nA + 1] = s_red[2] + s_red[3];
            }
            __syncthreads();
        }
    } else stream_wc1(a.se1w, a.WC1, 5 * 256 + hbid, tid);
    bt += GRID; gbar(a.bar, bt);

    // ---- P9: se1: cmidT[k,b] = relu((sl_d@WR1 + sl_p@WC1)/256 + b1) ----------
    {
        int id = gbid * 256 + tid;
        if (id < 65536) {
            int b = id >> 11, k = id & 2047;
            if (k < SEHID) {
                float acc = 0.f;
                const float* slr = a.sl + b * 79;
                for (int i = 0; i < 79; i++)  acc += slr[i] * a.WR1[i * SEHID + k];
                const float* slp = a.sl + NDRUG + b * 192;
                for (int i = 0; i < 192; i++) acc += slp[i] * a.WC1[i * SEHID + k];
                float v = fmaxf(acc * (1.f / 256.f) + a.se1b[k], 0.f);
                a.cmidT[k * 32 + b] = v;
            }
        }
    }
}

// =============================== TAIL ==========================================
__global__ __launch_bounds__(BLK, 2) void tail(TailArgs a) {
    const int gbid = blockIdx.x;
    const int tid  = threadIdx.x;
    int bt = 0;
    __shared__ float cs[125 * 32];      // 16 KB

    // ---- P0: se2 split-K partials (480 active blocks) -------------------------
    if (gbid < 480) {
        int bx = gbid % 30, by = gbid / 30;
        const int c0 = bx * 512 + tid * 2;
        const int ks = by * 125;
        const float4* csrc = (const float4*)(a.cmidT + ks * 32);
        for (int idx = tid; idx < 1000; idx += 256)
            ((float4*)cs)[idx] = csrc[idx];
        __syncthreads();
        const bool in = c0 < SEIN;
        float acc0[32], acc1[32];
#pragma unroll
        for (int b = 0; b < 32; b++) { acc0[b] = 0.f; acc1[b] = 0.f; }
        const float2* wp = (const float2*)(a.se2w + (size_t)ks * SEIN) + ((in ? c0 : 0) >> 1);
        const size_t wstr = SEIN / 2;
        for (int kk = 0; kk < 125; kk += 25) {
            float2 w[25];
#pragma unroll
            for (int t = 0; t < 25; t++) w[t] = wp[(size_t)t * wstr];
            wp += 25 * wstr;
#pragma unroll
            for (int t = 0; t < 25; t++) {
                const float* cp = cs + (kk + t) * 32;
#pragma unroll
                for (int b4 = 0; b4 < 32; b4 += 4) {
                    float4 c4 = *(const float4*)(cp + b4);
                    acc0[b4 + 0] += c4.x * w[t].x;  acc1[b4 + 0] += c4.x * w[t].y;
                    acc0[b4 + 1] += c4.y * w[t].x;  acc1[b4 + 1] += c4.y * w[t].y;
                    acc0[b4 + 2] += c4.z * w[t].x;  acc1[b4 + 2] += c4.z * w[t].y;
                    acc0[b4 + 3] += c4.w * w[t].x;  acc1[b4 + 3] += c4.w * w[t].y;
                }
            }
        }
        if (in) {
            float* pb = a.part + (size_t)by * (32 * SEIN) + c0;
#pragma unroll
            for (int b = 0; b < 32; b++) {
                float2 v; v.x = acc0[b]; v.y = acc1[b];
                *(float2*)(pb + (size_t)b * SEIN) = v;
            }
        }
    }
    bt += GRID; gbar(a.bar, bt);

    // ---- P1: reduce partials + bias, sigmoid, / inter -------------------------
    for (int gid = gbid * 256 + tid; gid < 32 * SEIN; gid += GRID * BLK) {
        int ij = gid % SEIN;
        float s = a.se2b[ij];
#pragma unroll
        for (int p = 0; p < NSPLIT; p++) s += a.part[(size_t)p * (32 * SEIN) + gid];
        float sig = 1.f / (1.f + __expf(-s));
        a.wgt[gid] = sig / a.inter[gid];
    }
    bt += GRID; gbar(a.bar, bt);

    // ---- P2: row/col sums of wgt ---------------------------------------------
    if (gbid < 32) {
        int b = gbid, t = tid;
        if (t < 192) {
            float s = 0.f;
            for (int i = 0; i < 79; i++) s += a.wgt[b * SEIN + i * 192 + t];
            a.wc[b * 192 + t] = s;
        }
        int wv = t >> 6, ln = t & 63;
        for (int i = wv; i < 79; i += 4) {
            float v = 0.f;
            for (int jj = ln; jj < 192; jj += 64) v += a.wgt[b * SEIN + i * 192 + jj];
            v += __shfl_down(v, 32); v += __shfl_down(v, 16); v += __shfl_down(v, 8);
            v += __shfl_down(v, 4);  v += __shfl_down(v, 2);  v += __shfl_down(v, 1);
            if (ln == 0) a.wr[b * 79 + i] = v;
        }
    }
    bt += GRID; gbar(a.bar, bt);

    // ---- P3: xx --------------------------------------------------------------
    if (gbid < 32) {
        int b = gbid, t = tid;
        float acc = 0.f;
        if (t < 128) {
            for (int i = 0; i < 79; i++)
                acc += a.xsum[(size_t)(b * 79 + i) * 128 + t] * a.wr[b * 79 + i];
        } else {
            int f = t - 128;
            for (int jj = 0; jj < 192; jj++)
                acc += a.xsum[(size_t)(NDRUG + b * 192 + jj) * 128 + f] * a.wc[b * 192 + jj];
        }
        a.xx[b * 256 + t] = acc * (1.f / 15168.f);
    }
    bt += GRID; gbar(a.bar, bt);

    // ---- P4..P7: head MLP, one output per thread -----------------------------
    {
        int id = gbid * 256 + tid;          // fc1: 32x512, K=256
        if (id < 32 * 512) {
            int b = id >> 9, col = id & 511;
            const float* ap = a.xx + b * 256;
            float acc = 0.f;
            for (int k = 0; k < 256; k++) acc += ap[k] * a.fc1w[(size_t)k * 512 + col];
            float v = acc + a.fc1b[col];
            a.out[32 + b * 512 + col] = v;          // raw h1
            a.r1[b * 512 + col] = fmaxf(v, 0.f);
        }
    }
    bt += GRID; gbar(a.bar, bt);
    {
        int id = gbid * 256 + tid;          // fc2: 32x256, K=512
        if (id < 32 * 256) {
            int b = id >> 8, col = id & 255;
            const float* ap = a.r1 + b * 512;
            float acc = 0.f;
            for (int k = 0; k < 512; k++) acc += ap[k] * a.fc2w[(size_t)k * 256 + col];
            a.r2[b * 256 + col] = fmaxf(acc + a.fc2b[col], 0.f);
        }
    }
    bt += GRID; gbar(a.bar, bt);
    {
        int id = gbid * 256 + tid;          // fc3: 32x128, K=256
        if (id < 32 * 128) {
            int b = id >> 7, col = id & 127;
            const float* ap = a.r2 + b * 256;
            float acc = 0.f;
            for (int k = 0; k < 256; k++) acc += ap[k] * a.fc3w[(size_t)k * 128 + col];
            a.r3[b * 128 + col] = fmaxf(acc + a.fc3b[col], 0.f);
        }
    }
    bt += GRID; gbar(a.bar, bt);
    {
        int id = gbid * 256 + tid;          // fc4: 32x64, K=128
        if (id < 32 * 64) {
            int b = id >> 6, col = id & 63;
            const float* ap = a.r3 + b * 128;
            float acc = 0.f;
            for (int k = 0; k < 128; k++) acc += ap[k] * a.fc4w[(size_t)k * 64 + col];
            a.r4[b * 64 + col] = fmaxf(acc + a.fc4b[col], 0.f);
        }
    }
    bt += GRID; gbar(a.bar, bt);
    // ---- P8: final 64->1 ------------------------------------------------------
    if (gbid == 0) {
        int b = tid >> 3, l = tid & 7;
        float v = 0.f;
        for (int jj = l; jj < 64; jj += 8) v += a.r4[b * 64 + jj] * a.outw[jj];
        v += __shfl_down(v, 4); v += __shfl_down(v, 2); v += __shfl_down(v, 1);
        if (l == 0) a.out[b] = v + a.outb[0];
    }
}

extern "C" void kernel_launch(void* const* d_in, const int* in_sizes, int n_in,
                              void* d_out, int out_size, void* d_ws, size_t ws_size,
                              hipStream_t stream) {
    const float* x1    = (const float*)d_in[0];
    const float* x2    = (const float*)d_in[1];
    const float* inter = (const float*)d_in[2];
    const int*   de    = (const int*)d_in[3];
    const int*   pe    = (const int*)d_in[4];
    const float* w1    = (const float*)d_in[5];
    const float* b1    = (const float*)d_in[6];
    const float* w2    = (const float*)d_in[7];
    const float* b2    = (const float*)d_in[8];
    const float* gw    = (const float*)d_in[9];
    const float* gas   = (const float*)d_in[10];
    const float* gad   = (const float*)d_in[11];
    const float* gb    = (const float*)d_in[12];
    const float* se1w  = (const float*)d_in[13];
    const float* se1b  = (const float*)d_in[14];
    const float* se2w  = (const float*)d_in[15];
    const float* se2b  = (const float*)d_in[16];
    const float* fc1w  = (const float*)d_in[17];
    const float* fc1b  = (const float*)d_in[18];
    const float* fc2w  = (const float*)d_in[19];
    const float* fc2b  = (const float*)d_in[20];
    const float* fc3w  = (const float*)d_in[21];
    const float* fc3b  = (const float*)d_in[22];
    const float* fc4w  = (const float*)d_in[23];
    const float* fc4b  = (const float*)d_in[24];
    const float* outw  = (const float*)d_in[25];
    const float* outb  = (const float*)d_in[26];
    float* out = (float*)d_out;
    float* ws  = (float*)d_ws;

    const size_t NF = (size_t)NTOT * 128;
    float* xA    = ws;
    float* xB    = xA + NF;
    float* hbuf  = xB + NF;
    float* xsum  = hbuf + NF;
    float* asn   = xsum + NF;
    float* adn   = asn + NTOT;
    float* sl    = adn + NTOT;
    float* WR1   = sl + NTOT;
    float* WC1   = WR1 + 79 * SEHID;
    float* cmidT = WC1 + 192 * SEHID;
    float* wgt   = cmidT + 32 * SEHID;
    float* wr    = wgt + 32 * SEIN;
    float* wc    = wr + 32 * 79;
    float* xx    = wc + 32 * 192;
    float* r1    = xx + 32 * 256;
    float* r2    = r1 + 32 * 512;
    float* r3    = r2 + 32 * 256;
    float* r4    = r3 + 32 * 128;
    float* part  = r4 + 32 * 64;
    int*   deg   = (int*)(part + (size_t)NSPLIT * 32 * SEIN);
    int*   fill  = deg + NTOT;
    int*   off   = fill + NTOT;
    int*   eidx  = off + NTOT + 1;
    int*   barF  = eidx + ETOT + 32;    // barrier counters (cache-line separated)
    int*   barT  = barF + 64;

    hipMemsetAsync(barF, 0, 2 * 64 * sizeof(int), stream);

    FrontArgs fa = { x1, x2, w1, b1, w2, b2, gw, gas, gad, gb, se1w, se1b,
                     de, pe,
                     xA, xB, hbuf, xsum, asn, adn, sl, WR1, WC1, cmidT,
                     deg, fill, off, eidx, barF };
    front<<<GRID, BLK, 0, stream>>>(fa);

    TailArgs ta = { cmidT, se2w, se2b, inter, xsum,
                    fc1w, fc1b, fc2w, fc2b, fc3w, fc3b, fc4w, fc4b, outw, outb,
                    part, wgt, wr, wc, xx, r1, r2, r3, r4, out, barT };
    tail<<<GRID, BLK, 0, stream>>>(ta);
}

// Round 5
// 627.982 us; speedup vs baseline: 4.6630x; 4.6630x over previous
//
#include <hip/hip_runtime.h>

#define NDRUG 2528   // 32*79
#define NPROT 6144   // 32*192
#define NTOT  8672
#define EDRUG 5120
#define EPROT 12800
#define ETOT  17920
#define SEIN  15168
#define SEHID 2000
#define NSPLIT 16

// ---------------- whole CSR build in ONE 1024-thread block ----------------------
// deg/scan/fill all in LDS; off[] and eidx[] written to global for gather.
__global__ __launch_bounds__(1024) void csr_one(const int* __restrict__ de,
                                                const int* __restrict__ pe,
                                                int* __restrict__ off,
                                                int* __restrict__ eidx) {
    __shared__ int ldeg[NTOT];      // 34.7 KB
    __shared__ int tot[1024];
    const int t = threadIdx.x;
    for (int i = t; i < NTOT; i += 1024) ldeg[i] = 0;
    __syncthreads();
    for (int e = t; e < ETOT; e += 1024) {
        int d;
        if (e < EDRUG) d = de[EDRUG + e];
        else d = pe[EPROT + (e - EDRUG)] + NDRUG;
        atomicAdd(&ldeg[d], 1);
    }
    __syncthreads();
    int loc[9];
    int s = 0;
    const int base = t * 9;         // 1024*9 = 9216 >= NTOT
#pragma unroll
    for (int c = 0; c < 9; c++) {
        int idx = base + c;
        int v = (idx < NTOT) ? ldeg[idx] : 0;
        loc[c] = s; s += v;
    }
    tot[t] = s;
    __syncthreads();
    for (int d = 1; d < 1024; d <<= 1) {
        int v = (t >= d) ? tot[t - d] : 0;
        __syncthreads();
        tot[t] += v;
        __syncthreads();
    }
    int pre = (t == 0) ? 0 : tot[t - 1];
#pragma unroll
    for (int c = 0; c < 9; c++) {
        int idx = base + c;
        if (idx < NTOT) { int o = pre + loc[c]; off[idx] = o; ldeg[idx] = o; }
    }
    if (t == 1023) off[NTOT] = tot[1023];
    __syncthreads();
    for (int e = t; e < ETOT; e += 1024) {
        int s2, d;
        if (e < EDRUG) { s2 = de[e]; d = de[EDRUG + e]; }
        else { int ep = e - EDRUG; s2 = pe[ep] + NDRUG; d = pe[EPROT + ep] + NDRUG; }
        int pos = atomicAdd(&ldeg[d], 1);
        eidx[pos] = s2;
    }
}

// ---------------- node MLP, BOTH layers fused (row-local dependency) ------------
__global__ void mlp12(const float* __restrict__ x1, const float* __restrict__ x2,
                      const float* __restrict__ w1, const float* __restrict__ b1,
                      const float* __restrict__ w2, const float* __restrict__ b2,
                      float* __restrict__ xA) {
    __shared__ float al[16 * 52];
    __shared__ float hl[16 * 128];
    const int bx = blockIdx.x;      // 542 blocks
    const int j  = threadIdx.x;     // 128 threads
    const int r0 = bx * 16;
    const float* A = (r0 >= NDRUG) ? x2 + (size_t)(r0 - NDRUG) * 52
                                   : x1 + (size_t)r0 * 52;
    for (int idx = j; idx < 16 * 52; idx += 128) al[idx] = A[idx];
    __syncthreads();
    float acc[16];
#pragma unroll
    for (int r = 0; r < 16; r++) acc[r] = 0.f;
    for (int k = 0; k < 52; k++) {
        float bv = w1[k * 128 + j];
#pragma unroll
        for (int r = 0; r < 16; r++) acc[r] += al[r * 52 + k] * bv;
    }
    float bb = b1[j];
#pragma unroll
    for (int r = 0; r < 16; r++) hl[r * 128 + j] = fmaxf(acc[r] + bb, 0.f);
    __syncthreads();
#pragma unroll
    for (int r = 0; r < 16; r++) acc[r] = 0.f;
    for (int k = 0; k < 128; k++) {
        float bv = w2[k * 128 + j];
#pragma unroll
        for (int r = 0; r < 16; r++) acc[r] += hl[r * 128 + k] * bv;
    }
    bb = b2[j];
#pragma unroll
    for (int r = 0; r < 16; r++)
        xA[(size_t)(r0 + r) * 128 + j] = fmaxf(acc[r] + bb, 0.f);
}

// ---------------- GAT: h = x@W (K=N=128) + per-node as/ad; drug+prot merged -----
__global__ void gat_h2(const float* __restrict__ X, const float* __restrict__ gw,
                       const float* __restrict__ gas, const float* __restrict__ gad,
                       int l, float* __restrict__ H, float* __restrict__ asn,
                       float* __restrict__ adn) {
    __shared__ float al[16 * 128];
    __shared__ float hl[16][129];
    const int bx = blockIdx.x;
    int r0; const float *W, *avs, *avd;
    if (bx < 158) {
        r0 = bx * 16;
        W = gw + (size_t)l * 16384; avs = gas + l * 128; avd = gad + l * 128;
    } else {
        r0 = NDRUG + (bx - 158) * 16;
        W = gw + (size_t)(l + 3) * 16384; avs = gas + (l + 3) * 128; avd = gad + (l + 3) * 128;
    }
    const int j = threadIdx.x;   // 128 threads
    for (int idx = j; idx < 16 * 128; idx += 128) al[idx] = X[(size_t)r0 * 128 + idx];
    __syncthreads();
    float acc[16];
#pragma unroll
    for (int r = 0; r < 16; r++) acc[r] = 0.f;
    for (int k = 0; k < 128; k++) {
        float bv = W[k * 128 + j];
#pragma unroll
        for (int r = 0; r < 16; r++) acc[r] += al[r * 128 + k] * bv;
    }
#pragma unroll
    for (int r = 0; r < 16; r++) {
        H[(size_t)(r0 + r) * 128 + j] = acc[r];
        hl[r][j] = acc[r];
    }
    __syncthreads();
    int r = j >> 3, l8 = j & 7;
    float ps = 0.f, pd = 0.f;
    for (int jj = l8; jj < 128; jj += 8) {
        float v = hl[r][jj];
        ps += v * avs[jj];
        pd += v * avd[jj];
    }
    ps += __shfl_down(ps, 4); ps += __shfl_down(ps, 2); ps += __shfl_down(ps, 1);
    pd += __shfl_down(pd, 4); pd += __shfl_down(pd, 2); pd += __shfl_down(pd, 1);
    if (l8 == 0) { asn[r0 + r] = ps; adn[r0 + r] = pd; }
}

// ---------------- GAT gather; last layer fuses rowsum (2 nodes per block) -------
__global__ void gat_gather(const int* __restrict__ off, const int* __restrict__ eidx,
                           const float* __restrict__ asn, const float* __restrict__ adn,
                           const float* __restrict__ H, const float* __restrict__ bd,
                           const float* __restrict__ bp, float* __restrict__ Xo,
                           float* __restrict__ xsum, float* __restrict__ sl,
                           int first, int last) {
    __shared__ float sred[4];
    int gid = blockIdx.x * 256 + threadIdx.x;   // NTOT*128 exactly
    int i = gid >> 7, f = gid & 127;
    float adi = adn[i];
    float ev = asn[i] + adi;
    ev = (ev > 0.f) ? ev : 0.2f * ev;
    float w = __expf(ev);                        // self loop
    float acc = w * H[(size_t)i * 128 + f];
    float den = w;
    int e0 = off[i], e1 = off[i + 1];
    for (int e = e0; e < e1; e++) {
        int s = eidx[e];
        float es = asn[s] + adi;
        es = (es > 0.f) ? es : 0.2f * es;
        float we = __expf(es);
        acc += we * H[(size_t)s * 128 + f];
        den += we;
    }
    float bias = (i < NDRUG) ? bd[f] : bp[f];
    float val = fmaxf(acc / den + bias, 0.f);
    if (!last) {
        Xo[gid] = val;
        xsum[gid] = first ? val : (xsum[gid] + val);
    } else {
        float xs = xsum[gid] + val;              // x13 itself never consumed
        xsum[gid] = xs;
        int t = threadIdx.x;
        float rv = xs;
        rv += __shfl_down(rv, 32); rv += __shfl_down(rv, 16); rv += __shfl_down(rv, 8);
        rv += __shfl_down(rv, 4);  rv += __shfl_down(rv, 2);  rv += __shfl_down(rv, 1);
        if ((t & 63) == 0) sred[t >> 6] = rv;
        __syncthreads();
        if (t == 0) {
            int n0 = blockIdx.x * 2;             // 2 nodes per block
            sl[n0]     = sred[0] + sred[1];
            sl[n0 + 1] = sred[2] + sred[3];
        }
    }
}

// ---------------- WR1[i,k] = sum_j se1w[(i*192+j)*2000+k] (stream 121MB) --------
__global__ void wr1k(const float* __restrict__ W, float* __restrict__ WR1) {
    int k = blockIdx.y * 256 + threadIdx.x;
    int i = blockIdx.x;                       // 0..78
    if (k >= SEHID) return;
    const float* p = W + (size_t)(i * 192) * SEHID + k;
    float a0 = 0.f, a1 = 0.f, a2 = 0.f, a3 = 0.f;
    for (int j = 0; j < 192; j += 4) {
        a0 += p[0];
        a1 += p[(size_t)SEHID];
        a2 += p[2 * (size_t)SEHID];
        a3 += p[3 * (size_t)SEHID];
        p += 4 * (size_t)SEHID;
    }
    WR1[i * SEHID + k] = (a0 + a1) + (a2 + a3);
}

// ---------------- WC1[j,k] = sum_i se1w[(i*192+j)*2000+k] (L3-warm 2nd pass) ----
__global__ void wc1k(const float* __restrict__ W, float* __restrict__ WC1) {
    int k = blockIdx.y * 256 + threadIdx.x;
    int j = blockIdx.x;                       // 0..191
    if (k >= SEHID) return;
    const float* p = W + (size_t)j * SEHID + k;
    const size_t st = (size_t)192 * SEHID;
    float a0 = 0.f, a1 = 0.f, a2 = 0.f, a3 = 0.f;
    int i = 0;
    for (; i < 76; i += 4) {
        a0 += p[0]; a1 += p[st]; a2 += p[2 * st]; a3 += p[3 * st];
        p += 4 * st;
    }
    a0 += p[0]; a1 += p[st]; a2 += p[2 * st];   // 76,77,78
    WC1[j * SEHID + k] = (a0 + a1) + (a2 + a3);
}

// ---------------- cmidT[k,b] = relu((slr@WR1 + slp@WC1)/256 + b) ----------------
__global__ void se1_small(const float* __restrict__ sl, const float* __restrict__ WR1,
                          const float* __restrict__ WC1, const float* __restrict__ bias,
                          float* __restrict__ cmidT) {
    int k = blockIdx.x * 256 + threadIdx.x;   // grid.x = 8
    int b = blockIdx.y;                       // 32
    if (k >= SEHID) return;
    float acc = 0.f;
    const float* slr = sl + b * 79;
    for (int i = 0; i < 79; i++)  acc += slr[i] * WR1[i * SEHID + k];
    const float* slp = sl + NDRUG + b * 192;
    for (int j = 0; j < 192; j++) acc += slp[j] * WC1[j * SEHID + k];
    float v = fmaxf(acc * (1.f / 256.f) + bias[k], 0.f);
    cmidT[k * 32 + b] = v;
}

// ---------------- SE2 split-K partials: (32 x 2000) @ (2000 x 15168) ------------
__global__ __launch_bounds__(256) void se2p(const float* __restrict__ cmidT,
                                            const float* __restrict__ W,
                                            float* __restrict__ part) {
    __shared__ float cs[125 * 32];            // 16 KB
    const int tid = threadIdx.x;
    const int c0 = blockIdx.x * 512 + tid * 2;
    const int ks = blockIdx.y * 125;
    const float4* csrc = (const float4*)(cmidT + ks * 32);   // 16B-aligned
    for (int idx = tid; idx < 1000; idx += 256)
        ((float4*)cs)[idx] = csrc[idx];
    __syncthreads();
    const bool in = c0 < SEIN;
    float acc0[32], acc1[32];
#pragma unroll
    for (int b = 0; b < 32; b++) { acc0[b] = 0.f; acc1[b] = 0.f; }
    const float2* wp = (const float2*)(W + (size_t)ks * SEIN) + ((in ? c0 : 0) >> 1);
    const size_t wstr = SEIN / 2;             // float2 stride per k row
    for (int kk = 0; kk < 125; kk += 25) {
        float2 w[25];
#pragma unroll
        for (int t = 0; t < 25; t++) w[t] = wp[(size_t)t * wstr];
        wp += 25 * wstr;
#pragma unroll
        for (int t = 0; t < 25; t++) {
            const float* cp = cs + (kk + t) * 32;
#pragma unroll
            for (int b4 = 0; b4 < 32; b4 += 4) {
                float4 a = *(const float4*)(cp + b4);   // uniform addr -> LDS broadcast
                acc0[b4 + 0] += a.x * w[t].x;  acc1[b4 + 0] += a.x * w[t].y;
                acc0[b4 + 1] += a.y * w[t].x;  acc1[b4 + 1] += a.y * w[t].y;
                acc0[b4 + 2] += a.z * w[t].x;  acc1[b4 + 2] += a.z * w[t].y;
                acc0[b4 + 3] += a.w * w[t].x;  acc1[b4 + 3] += a.w * w[t].y;
            }
        }
    }
    if (in) {
        float* pb = part + (size_t)blockIdx.y * (32 * SEIN) + c0;
#pragma unroll
        for (int b = 0; b < 32; b++) {
            float2 v; v.x = acc0[b]; v.y = acc1[b];
            *(float2*)(pb + (size_t)b * SEIN) = v;
        }
    }
}

// ---------------- se2 reduce + sigmoid + /inter + row/col sums + xx, per b ------
// One block per batch row; wgt row lives entirely in LDS (never hits HBM).
__global__ __launch_bounds__(256) void setail(const float* __restrict__ part,
                                              const float* __restrict__ se2b,
                                              const float* __restrict__ inter,
                                              const float* __restrict__ xsum,
                                              float* __restrict__ xx) {
    __shared__ float wl[SEIN];                // 60672 B
    __shared__ float wrl[80];
    __shared__ float wcl[192];
    const int b = blockIdx.x, t = threadIdx.x;
    for (int ij = t; ij < SEIN; ij += 256) {
        float s = se2b[ij];
#pragma unroll
        for (int p = 0; p < NSPLIT; p++)
            s += part[(size_t)p * (32 * SEIN) + (size_t)b * SEIN + ij];
        float sig = 1.f / (1.f + __expf(-s));
        wl[ij] = sig / inter[(size_t)b * SEIN + ij];
    }
    __syncthreads();
    if (t < 192) {                             // column sums
        float s = 0.f;
        for (int i = 0; i < 79; i++) s += wl[i * 192 + t];
        wcl[t] = s;
    }
    int wv = t >> 6, ln = t & 63;              // row sums: one wave per row
    for (int i = wv; i < 79; i += 4) {
        float v = 0.f;
        for (int j = ln; j < 192; j += 64) v += wl[i * 192 + j];
        v += __shfl_down(v, 32); v += __shfl_down(v, 16); v += __shfl_down(v, 8);
        v += __shfl_down(v, 4);  v += __shfl_down(v, 2);  v += __shfl_down(v, 1);
        if (ln == 0) wrl[i] = v;
    }
    __syncthreads();
    float acc = 0.f;
    if (t < 128) {
        for (int i = 0; i < 79; i++)
            acc += xsum[(size_t)(b * 79 + i) * 128 + t] * wrl[i];
    } else {
        int f = t - 128;
        for (int j = 0; j < 192; j++)
            acc += xsum[(size_t)(NDRUG + b * 192 + j) * 128 + f] * wcl[j];
    }
    xx[b * 256 + t] = acc * (1.f / 15168.f);
}

// ---------------- head MLP: fc1..fc4 + out, one block per batch row -------------
__global__ __launch_bounds__(256) void headk(const float* __restrict__ xx,
                                             const float* __restrict__ fc1w, const float* __restrict__ fc1b,
                                             const float* __restrict__ fc2w, const float* __restrict__ fc2b,
                                             const float* __restrict__ fc3w, const float* __restrict__ fc3b,
                                             const float* __restrict__ fc4w, const float* __restrict__ fc4b,
                                             const float* __restrict__ outw, const float* __restrict__ outb,
                                             float* __restrict__ out) {
    __shared__ float a0[256], a1[512], a2[256], a3[128], a4[64];
    const int b = blockIdx.x, t = threadIdx.x;
    a0[t] = xx[b * 256 + t];
    __syncthreads();
    for (int c = t; c < 512; c += 256) {       // fc1 (raw h1 is output 1)
        float acc = 0.f;
        for (int k = 0; k < 256; k++) acc += a0[k] * fc1w[(size_t)k * 512 + c];
        float v = acc + fc1b[c];
        out[32 + b * 512 + c] = v;
        a1[c] = fmaxf(v, 0.f);
    }
    __syncthreads();
    {
        float acc = 0.f;                        // fc2
        for (int k = 0; k < 512; k++) acc += a1[k] * fc2w[(size_t)k * 256 + t];
        a2[t] = fmaxf(acc + fc2b[t], 0.f);
    }
    __syncthreads();
    if (t < 128) {                              // fc3
        float acc = 0.f;
        for (int k = 0; k < 256; k++) acc += a2[k] * fc3w[(size_t)k * 128 + t];
        a3[t] = fmaxf(acc + fc3b[t], 0.f);
    }
    __syncthreads();
    if (t < 64) {                               // fc4
        float acc = 0.f;
        for (int k = 0; k < 128; k++) acc += a3[k] * fc4w[(size_t)k * 64 + t];
        a4[t] = fmaxf(acc + fc4b[t], 0.f);
    }
    __syncthreads();
    if (t < 64) {                               // out: 64 -> 1
        float v = a4[t] * outw[t];
        v += __shfl_down(v, 32); v += __shfl_down(v, 16); v += __shfl_down(v, 8);
        v += __shfl_down(v, 4);  v += __shfl_down(v, 2);  v += __shfl_down(v, 1);
        if (t == 0) out[b] = v + outb[0];
    }
}

extern "C" void kernel_launch(void* const* d_in, const int* in_sizes, int n_in,
                              void* d_out, int out_size, void* d_ws, size_t ws_size,
                              hipStream_t stream) {
    const float* x1    = (const float*)d_in[0];
    const float* x2    = (const float*)d_in[1];
    const float* inter = (const float*)d_in[2];
    const int*   de    = (const int*)d_in[3];
    const int*   pe    = (const int*)d_in[4];
    const float* w1    = (const float*)d_in[5];
    const float* b1    = (const float*)d_in[6];
    const float* w2    = (const float*)d_in[7];
    const float* b2    = (const float*)d_in[8];
    const float* gw    = (const float*)d_in[9];
    const float* gas   = (const float*)d_in[10];
    const float* gad   = (const float*)d_in[11];
    const float* gb    = (const float*)d_in[12];
    const float* se1w  = (const float*)d_in[13];
    const float* se1b  = (const float*)d_in[14];
    const float* se2w  = (const float*)d_in[15];
    const float* se2b  = (const float*)d_in[16];
    const float* fc1w  = (const float*)d_in[17];
    const float* fc1b  = (const float*)d_in[18];
    const float* fc2w  = (const float*)d_in[19];
    const float* fc2b  = (const float*)d_in[20];
    const float* fc3w  = (const float*)d_in[21];
    const float* fc3b  = (const float*)d_in[22];
    const float* fc4w  = (const float*)d_in[23];
    const float* fc4b  = (const float*)d_in[24];
    const float* outw  = (const float*)d_in[25];
    const float* outb  = (const float*)d_in[26];
    float* out = (float*)d_out;
    float* ws  = (float*)d_ws;

    const size_t NF = (size_t)NTOT * 128;
    float* xA    = ws;
    float* xB    = xA + NF;
    float* hbuf  = xB + NF;
    float* xsum  = hbuf + NF;
    float* sm    = xsum + NF;
    float* asn   = sm;                     sm += NTOT;
    float* adn   = sm;                     sm += NTOT;
    float* sl    = sm;                     sm += NTOT;
    float* WR1   = sm;                     sm += 79 * SEHID;
    float* WC1   = sm;                     sm += 192 * SEHID;
    float* cmidT = sm;                     sm += 32 * SEHID;
    float* xx    = sm;                     sm += 32 * 256;
    float* part  = sm;                     sm += (size_t)NSPLIT * 32 * SEIN;
    int*   im    = (int*)sm;
    int*   off   = im;                     im += NTOT + 1;
    int*   eidx  = im;                     im += ETOT;

    // CSR build (single block, LDS-resident)
    csr_one<<<1, 1024, 0, stream>>>(de, pe, off, eidx);

    // SE1 weight reductions (independent; wc1k right after wr1k -> L3-warm)
    wr1k<<<dim3(79, 8), 256, 0, stream>>>(se1w, WR1);
    wc1k<<<dim3(192, 8), 256, 0, stream>>>(se1w, WC1);

    // node embedding MLP, both layers fused
    mlp12<<<542, 128, 0, stream>>>(x1, x2, w1, b1, w2, b2, xA);

    // 3 GAT layers; last gather fuses rowsum and skips dead x13 store
    gat_h2<<<542, 128, 0, stream>>>(xA, gw, gas, gad, 0, hbuf, asn, adn);
    gat_gather<<<4336, 256, 0, stream>>>(off, eidx, asn, adn, hbuf,
                                         gb + 0 * 128, gb + 3 * 128,
                                         xB, xsum, sl, 1, 0);
    gat_h2<<<542, 128, 0, stream>>>(xB, gw, gas, gad, 1, hbuf, asn, adn);
    gat_gather<<<4336, 256, 0, stream>>>(off, eidx, asn, adn, hbuf,
                                         gb + 1 * 128, gb + 4 * 128,
                                         xA, xsum, sl, 0, 0);
    gat_h2<<<542, 128, 0, stream>>>(xA, gw, gas, gad, 2, hbuf, asn, adn);
    gat_gather<<<4336, 256, 0, stream>>>(off, eidx, asn, adn, hbuf,
                                         gb + 2 * 128, gb + 5 * 128,
                                         nullptr, xsum, sl, 0, 1);

    // SE path
    se1_small<<<dim3(8, 32), 256, 0, stream>>>(sl, WR1, WC1, se1b, cmidT);
    se2p<<<dim3(30, NSPLIT), 256, 0, stream>>>(cmidT, se2w, part);
    setail<<<32, 256, 0, stream>>>(part, se2b, inter, xsum, xx);

    // head MLP fully fused
    headk<<<32, 256, 0, stream>>>(xx, fc1w, fc1b, fc2w, fc2b, fc3w, fc3b,
                                  fc4w, fc4b, outw, outb, out);
}

// Round 6
// 505.298 us; speedup vs baseline: 5.7951x; 1.2428x over previous
//
#include <hip/hip_runtime.h>

#define NDRUG 2528   // 32*79
#define NPROT 6144   // 32*192
#define NTOT  8672
#define EDRUG 5120
#define EPROT 12800
#define ETOT  17920
#define SEIN  15168
#define SEHID 2000
#define NSPLIT 16
#define NTOTF (NTOT*128)
#define ECAP  64

#define FMA4(A, s, W4) { A.x += (s)*(W4).x; A.y += (s)*(W4).y; A.z += (s)*(W4).z; A.w += (s)*(W4).w; }

// ================= K1: node-MLP (542) | wr1k stream (158) | CSR build (16) =====
__global__ __launch_bounds__(256) void k1(const float* __restrict__ x1,
                                          const float* __restrict__ x2,
                                          const float* __restrict__ w1,
                                          const float* __restrict__ b1,
                                          const float* __restrict__ w2,
                                          const float* __restrict__ b2,
                                          float* __restrict__ xA,
                                          const float* __restrict__ se1w,
                                          float* __restrict__ WR1,
                                          const int* __restrict__ de,
                                          const int* __restrict__ pe,
                                          int* __restrict__ cnt,
                                          int* __restrict__ eidxc) {
    __shared__ float al[16 * 52];
    __shared__ float hl[16 * 128];
    const int bx = blockIdx.x, tid = threadIdx.x;
    if (bx < 542) {                         // ---- node MLP, both layers
        const int u = tid >> 7, j = tid & 127;
        const int r0 = bx * 16;
        const float* A = (r0 >= NDRUG) ? x2 + (size_t)(r0 - NDRUG) * 52
                                       : x1 + (size_t)r0 * 52;
        for (int idx = tid; idx < 16 * 52; idx += 256) al[idx] = A[idx];
        __syncthreads();
        float acc[8];
#pragma unroll
        for (int r = 0; r < 8; r++) acc[r] = 0.f;
        for (int k4 = 0; k4 < 13; k4++) {
            float c0 = w1[(k4 * 4 + 0) * 128 + j];
            float c1 = w1[(k4 * 4 + 1) * 128 + j];
            float c2 = w1[(k4 * 4 + 2) * 128 + j];
            float c3 = w1[(k4 * 4 + 3) * 128 + j];
#pragma unroll
            for (int r = 0; r < 8; r++) {
                float4 av = ((const float4*)(al + (u * 8 + r) * 52))[k4];
                acc[r] += av.x * c0 + av.y * c1 + av.z * c2 + av.w * c3;
            }
        }
        float bb = b1[j];
#pragma unroll
        for (int r = 0; r < 8; r++) hl[(u * 8 + r) * 128 + j] = fmaxf(acc[r] + bb, 0.f);
        __syncthreads();
#pragma unroll
        for (int r = 0; r < 8; r++) acc[r] = 0.f;
        for (int k4 = 0; k4 < 32; k4++) {
            float c0 = w2[(k4 * 4 + 0) * 128 + j];
            float c1 = w2[(k4 * 4 + 1) * 128 + j];
            float c2 = w2[(k4 * 4 + 2) * 128 + j];
            float c3 = w2[(k4 * 4 + 3) * 128 + j];
#pragma unroll
            for (int r = 0; r < 8; r++) {
                float4 av = ((const float4*)(hl + (u * 8 + r) * 128))[k4];
                acc[r] += av.x * c0 + av.y * c1 + av.z * c2 + av.w * c3;
            }
        }
        bb = b2[j];
#pragma unroll
        for (int r = 0; r < 8; r++)
            xA[(size_t)(r0 + u * 8 + r) * 128 + j] = fmaxf(acc[r] + bb, 0.f);
    } else if (bx < 700) {                  // ---- WR1[i,k] = sum_j se1w[i,j,:,k]
        int rb = bx - 542;                  // 0..157
        int i = rb >> 1, half = rb & 1;
        int k4 = half * 256 + tid;
        if (k4 < 500) {
            const float4* p = (const float4*)se1w + (size_t)(i * 192) * 500 + k4;
            float4 acc = {0.f, 0.f, 0.f, 0.f};
            for (int j0 = 0; j0 < 192; j0 += 8) {
                float4 v[8];
#pragma unroll
                for (int t = 0; t < 8; t++) v[t] = p[(size_t)(j0 + t) * 500];
#pragma unroll
                for (int t = 0; t < 8; t++) {
                    acc.x += v[t].x; acc.y += v[t].y; acc.z += v[t].z; acc.w += v[t].w;
                }
            }
            ((float4*)(WR1 + i * SEHID))[k4] = acc;
        }
    } else {                                // ---- CSR one-pass (capped slots)
        int rb = bx - 700;                  // 0..15
        for (int e = rb * 256 + tid; e < ETOT; e += 16 * 256) {
            int s, d;
            if (e < EDRUG) { s = de[e]; d = de[EDRUG + e]; }
            else { int ep = e - EDRUG; s = pe[ep] + NDRUG; d = pe[EPROT + ep] + NDRUG; }
            int slot = atomicAdd(&cnt[d], 1);
            if (slot < ECAP) eidxc[(size_t)d * ECAP + slot] = s;
        }
    }
}

// ---------------- GAT h-tile device body (256 thr: 2 units x 8 rows) ------------
__device__ __forceinline__ void gat_h_body(const float* __restrict__ X,
                                           const float* __restrict__ gw,
                                           const float* __restrict__ gas,
                                           const float* __restrict__ gad,
                                           int l, float* __restrict__ H,
                                           float* __restrict__ asn, float* __restrict__ adn,
                                           int bx, int tid, float* al, float* hl) {
    const int u = tid >> 7, j = tid & 127;
    int r0; const float *W, *avs, *avd;
    if (bx < 158) {
        r0 = bx * 16;
        W = gw + (size_t)l * 16384; avs = gas + l * 128; avd = gad + l * 128;
    } else {
        r0 = NDRUG + (bx - 158) * 16;
        W = gw + (size_t)(l + 3) * 16384; avs = gas + (l + 3) * 128; avd = gad + (l + 3) * 128;
    }
    for (int idx = tid; idx < 2048; idx += 256) al[idx] = X[(size_t)r0 * 128 + idx];
    __syncthreads();
    float acc[8];
#pragma unroll
    for (int r = 0; r < 8; r++) acc[r] = 0.f;
    for (int k4 = 0; k4 < 32; k4++) {
        float c0 = W[(k4 * 4 + 0) * 128 + j];
        float c1 = W[(k4 * 4 + 1) * 128 + j];
        float c2 = W[(k4 * 4 + 2) * 128 + j];
        float c3 = W[(k4 * 4 + 3) * 128 + j];
#pragma unroll
        for (int r = 0; r < 8; r++) {
            float4 av = ((const float4*)(al + (u * 8 + r) * 128))[k4];
            acc[r] += av.x * c0 + av.y * c1 + av.z * c2 + av.w * c3;
        }
    }
#pragma unroll
    for (int r = 0; r < 8; r++) {
        H[(size_t)(r0 + u * 8 + r) * 128 + j] = acc[r];
        hl[(u * 8 + r) * 128 + j] = acc[r];
    }
    __syncthreads();
    int rl = j >> 4, l16 = j & 15;
    int row = u * 8 + rl;
    float ps = 0.f, pd = 0.f;
    for (int jj = l16; jj < 128; jj += 16) {
        float v = hl[row * 128 + jj];
        ps += v * avs[jj];
        pd += v * avd[jj];
    }
    ps += __shfl_down(ps, 8, 16); ps += __shfl_down(ps, 4, 16);
    ps += __shfl_down(ps, 2, 16); ps += __shfl_down(ps, 1, 16);
    pd += __shfl_down(pd, 8, 16); pd += __shfl_down(pd, 4, 16);
    pd += __shfl_down(pd, 2, 16); pd += __shfl_down(pd, 1, 16);
    if (l16 == 0) { asn[r0 + row] = ps; adn[r0 + row] = pd; }
}

// ================= K2: GAT-h L0 (542) | wc1k stream (384) ======================
__global__ __launch_bounds__(256) void k2(const float* __restrict__ X,
                                          const float* __restrict__ gw,
                                          const float* __restrict__ gas,
                                          const float* __restrict__ gad,
                                          float* __restrict__ H,
                                          float* __restrict__ asn,
                                          float* __restrict__ adn,
                                          const float* __restrict__ se1w,
                                          float* __restrict__ WC1) {
    __shared__ float al[2048];
    __shared__ float hl[2048];
    const int bx = blockIdx.x, tid = threadIdx.x;
    if (bx < 542) {
        gat_h_body(X, gw, gas, gad, 0, H, asn, adn, bx, tid, al, hl);
    } else {                                // ---- WC1[j,k] = sum_i se1w[i,j,:,k]
        int rb = bx - 542;                  // 0..383
        int j = rb >> 1, half = rb & 1;
        int k4 = half * 256 + tid;
        if (k4 < 500) {
            const float4* p = (const float4*)se1w + (size_t)j * 500 + k4;
            const size_t st = (size_t)192 * 500;
            float4 acc = {0.f, 0.f, 0.f, 0.f};
            int i = 0;
            for (; i + 8 <= 72; i += 8) {
                float4 v[8];
#pragma unroll
                for (int t = 0; t < 8; t++) v[t] = p[(size_t)(i + t) * st];
#pragma unroll
                for (int t = 0; t < 8; t++) {
                    acc.x += v[t].x; acc.y += v[t].y; acc.z += v[t].z; acc.w += v[t].w;
                }
            }
            for (; i < 79; i++) {
                float4 v = p[(size_t)i * st];
                acc.x += v.x; acc.y += v.y; acc.z += v.z; acc.w += v.w;
            }
            ((float4*)(WC1 + j * SEHID))[k4] = acc;
        }
    }
}

// ================= standalone GAT-h (layers 1,2) ===============================
__global__ __launch_bounds__(256) void gath(const float* __restrict__ X,
                                            const float* __restrict__ gw,
                                            const float* __restrict__ gas,
                                            const float* __restrict__ gad,
                                            int l, float* __restrict__ H,
                                            float* __restrict__ asn,
                                            float* __restrict__ adn) {
    __shared__ float al[2048];
    __shared__ float hl[2048];
    gat_h_body(X, gw, gas, gad, l, H, asn, adn, blockIdx.x, threadIdx.x, al, hl);
}

// ================= GAT gather; last layer fuses rowsum =========================
__global__ __launch_bounds__(256) void gat_gather(const int* __restrict__ cnt,
                                                  const int* __restrict__ eidxc,
                                                  const float* __restrict__ asn,
                                                  const float* __restrict__ adn,
                                                  const float* __restrict__ H,
                                                  const float* __restrict__ bd,
                                                  const float* __restrict__ bp,
                                                  float* __restrict__ Xo,
                                                  float* __restrict__ xsum,
                                                  float* __restrict__ sl,
                                                  int first, int last) {
    __shared__ float sred[4];
    int gid = blockIdx.x * 256 + threadIdx.x;   // NTOT*128 exactly
    int i = gid >> 7, f = gid & 127;
    float adi = adn[i];
    float ev = asn[i] + adi;
    ev = (ev > 0.f) ? ev : 0.2f * ev;
    float w = __expf(ev);                        // self loop
    float acc = w * H[(size_t)i * 128 + f];
    float den = w;
    int dg = cnt[i]; dg = dg > ECAP ? ECAP : dg;
    const int* ep = eidxc + (size_t)i * ECAP;
    for (int e = 0; e < dg; e++) {
        int s = ep[e];
        float es = asn[s] + adi;
        es = (es > 0.f) ? es : 0.2f * es;
        float we = __expf(es);
        acc += we * H[(size_t)s * 128 + f];
        den += we;
    }
    float bias = (i < NDRUG) ? bd[f] : bp[f];
    float val = fmaxf(acc / den + bias, 0.f);
    if (!last) {
        Xo[gid] = val;
        xsum[gid] = first ? val : (xsum[gid] + val);
    } else {
        float xs = xsum[gid] + val;
        xsum[gid] = xs;
        int t = threadIdx.x;
        float rv = xs;
        rv += __shfl_down(rv, 32); rv += __shfl_down(rv, 16); rv += __shfl_down(rv, 8);
        rv += __shfl_down(rv, 4);  rv += __shfl_down(rv, 2);  rv += __shfl_down(rv, 1);
        if ((t & 63) == 0) sred[t >> 6] = rv;
        __syncthreads();
        if (t == 0) {
            int n0 = blockIdx.x * 2;
            sl[n0]     = sred[0] + sred[1];
            sl[n0 + 1] = sred[2] + sred[3];
        }
    }
}

// ================= cmidT[k,b] = relu((sl_d@WR1 + sl_p@WC1)/256 + b) ============
__global__ __launch_bounds__(256) void se1_small(const float* __restrict__ sl,
                                                 const float* __restrict__ WR1,
                                                 const float* __restrict__ WC1,
                                                 const float* __restrict__ bias,
                                                 float* __restrict__ cmidT) {
    int k = blockIdx.x * 256 + threadIdx.x;   // grid.x = 8
    int b = blockIdx.y;                       // 32
    if (k >= SEHID) return;
    float acc = 0.f;
    const float* slr = sl + b * 79;
    for (int i = 0; i < 79; i++)  acc += slr[i] * WR1[i * SEHID + k];
    const float* slp = sl + NDRUG + b * 192;
    for (int j = 0; j < 192; j++) acc += slp[j] * WC1[j * SEHID + k];
    float v = fmaxf(acc * (1.f / 256.f) + bias[k], 0.f);
    cmidT[k * 32 + b] = v;
}

// ================= SE2 split-K partials; 4 cols/thread =========================
__global__ __launch_bounds__(256, 1) void se2p(const float* __restrict__ cmidT,
                                               const float* __restrict__ W,
                                               float* __restrict__ part) {
    __shared__ float4 cs4[125 * 8];           // 125 k x 32 b = 16 KB
    const int tid = threadIdx.x;
    const int c4 = blockIdx.x * 256 + tid;    // float4-column index
    const int ks = blockIdx.y * 125;
    const float4* csrc = (const float4*)(cmidT + ks * 32);
    for (int idx = tid; idx < 1000; idx += 256) cs4[idx] = csrc[idx];
    __syncthreads();
    const bool in = c4 < (SEIN / 4);          // 3792
    float4 acc[32];
#pragma unroll
    for (int b = 0; b < 32; b++) acc[b] = make_float4(0.f, 0.f, 0.f, 0.f);
    const float4* wp = (const float4*)W + (size_t)ks * (SEIN / 4) + (in ? c4 : 0);
    int kk = 0;
    for (int bt = 0; bt < 12; bt++) {         // 12 batches of 10
        float4 wv[10];
#pragma unroll
        for (int t = 0; t < 10; t++) wv[t] = wp[(size_t)t * (SEIN / 4)];
        wp += (size_t)10 * (SEIN / 4);
#pragma unroll
        for (int t = 0; t < 10; t++) {
            const float4* cp = cs4 + (kk + t) * 8;
#pragma unroll
            for (int b8 = 0; b8 < 8; b8++) {
                float4 a = cp[b8];
                FMA4(acc[b8 * 4 + 0], a.x, wv[t]);
                FMA4(acc[b8 * 4 + 1], a.y, wv[t]);
                FMA4(acc[b8 * 4 + 2], a.z, wv[t]);
                FMA4(acc[b8 * 4 + 3], a.w, wv[t]);
            }
        }
        kk += 10;
    }
    {                                         // tail batch of 5 (k 120..124)
        float4 wv[5];
#pragma unroll
        for (int t = 0; t < 5; t++) wv[t] = wp[(size_t)t * (SEIN / 4)];
#pragma unroll
        for (int t = 0; t < 5; t++) {
            const float4* cp = cs4 + (kk + t) * 8;
#pragma unroll
            for (int b8 = 0; b8 < 8; b8++) {
                float4 a = cp[b8];
                FMA4(acc[b8 * 4 + 0], a.x, wv[t]);
                FMA4(acc[b8 * 4 + 1], a.y, wv[t]);
                FMA4(acc[b8 * 4 + 2], a.z, wv[t]);
                FMA4(acc[b8 * 4 + 3], a.w, wv[t]);
            }
        }
    }
    if (in) {
        float* pb = part + (size_t)blockIdx.y * (32 * SEIN) + (size_t)c4 * 4;
#pragma unroll
        for (int b = 0; b < 32; b++)
            *(float4*)(pb + (size_t)b * SEIN) = acc[b];
    }
}

// ================= reduce partials + bias, sigmoid, / inter -> wgt =============
__global__ __launch_bounds__(256) void se2fin(const float* __restrict__ part,
                                              const float* __restrict__ se2b,
                                              const float* __restrict__ inter,
                                              float* __restrict__ wgt) {
    int gid = blockIdx.x * 256 + threadIdx.x;   // 1896*256 = 485376 exactly
    int ij = gid % SEIN;
    float s = se2b[ij];
#pragma unroll
    for (int p = 0; p < NSPLIT; p++) s += part[(size_t)p * (32 * SEIN) + gid];
    float sig = 1.f / (1.f + __expf(-s));
    wgt[gid] = sig / inter[gid];
}

// ================= per-b tail: wsum + xx + head MLP + out ======================
__global__ __launch_bounds__(256) void tail32(const float* __restrict__ wgt,
                                              const float* __restrict__ xsum,
                                              const float* __restrict__ fc1w, const float* __restrict__ fc1b,
                                              const float* __restrict__ fc2w, const float* __restrict__ fc2b,
                                              const float* __restrict__ fc3w, const float* __restrict__ fc3b,
                                              const float* __restrict__ fc4w, const float* __restrict__ fc4b,
                                              const float* __restrict__ outw, const float* __restrict__ outb,
                                              float* __restrict__ out) {
    __shared__ float wl[SEIN];
    __shared__ float wrl[79], wcl[192];
    __shared__ float xxl[256], h1[512], h2[256], h3[128], h4[64];
    const int b = blockIdx.x, t = threadIdx.x;
    for (int idx = t; idx < SEIN / 4; idx += 256)
        ((float4*)wl)[idx] = ((const float4*)(wgt + (size_t)b * SEIN))[idx];
    __syncthreads();
    if (t < 192) {                             // column sums
        float s = 0.f;
        for (int i = 0; i < 79; i++) s += wl[i * 192 + t];
        wcl[t] = s;
    }
    int wv = t >> 6, ln = t & 63;              // row sums
    for (int i = wv; i < 79; i += 4) {
        float v = 0.f;
        for (int j = ln; j < 192; j += 64) v += wl[i * 192 + j];
        v += __shfl_down(v, 32); v += __shfl_down(v, 16); v += __shfl_down(v, 8);
        v += __shfl_down(v, 4);  v += __shfl_down(v, 2);  v += __shfl_down(v, 1);
        if (ln == 0) wrl[i] = v;
    }
    __syncthreads();
    {
        float acc = 0.f;
        if (t < 128) {
            for (int i = 0; i < 79; i++)
                acc += xsum[(size_t)(b * 79 + i) * 128 + t] * wrl[i];
        } else {
            int f = t - 128;
            for (int j = 0; j < 192; j++)
                acc += xsum[(size_t)(NDRUG + b * 192 + j) * 128 + f] * wcl[j];
        }
        xxl[t] = acc * (1.f / 15168.f);
    }
    __syncthreads();
    for (int c = t; c < 512; c += 256) {       // fc1 (raw h1 is output 1)
        float acc = 0.f;
        for (int k = 0; k < 256; k++) acc += xxl[k] * fc1w[(size_t)k * 512 + c];
        float v = acc + fc1b[c];
        out[32 + b * 512 + c] = v;
        h1[c] = fmaxf(v, 0.f);
    }
    __syncthreads();
    {
        float acc = 0.f;                        // fc2
        for (int k = 0; k < 512; k++) acc += h1[k] * fc2w[(size_t)k * 256 + t];
        h2[t] = fmaxf(acc + fc2b[t], 0.f);
    }
    __syncthreads();
    if (t < 128) {                              // fc3
        float acc = 0.f;
        for (int k = 0; k < 256; k++) acc += h2[k] * fc3w[(size_t)k * 128 + t];
        h3[t] = fmaxf(acc + fc3b[t], 0.f);
    }
    __syncthreads();
    if (t < 64) {                               // fc4
        float acc = 0.f;
        for (int k = 0; k < 128; k++) acc += h3[k] * fc4w[(size_t)k * 64 + t];
        h4[t] = fmaxf(acc + fc4b[t], 0.f);
    }
    __syncthreads();
    if (t < 64) {                               // out: 64 -> 1
        float v = h4[t] * outw[t];
        v += __shfl_down(v, 32); v += __shfl_down(v, 16); v += __shfl_down(v, 8);
        v += __shfl_down(v, 4);  v += __shfl_down(v, 2);  v += __shfl_down(v, 1);
        if (t == 0) out[b] = v + outb[0];
    }
}

extern "C" void kernel_launch(void* const* d_in, const int* in_sizes, int n_in,
                              void* d_out, int out_size, void* d_ws, size_t ws_size,
                              hipStream_t stream) {
    const float* x1    = (const float*)d_in[0];
    const float* x2    = (const float*)d_in[1];
    const float* inter = (const float*)d_in[2];
    const int*   de    = (const int*)d_in[3];
    const int*   pe    = (const int*)d_in[4];
    const float* w1    = (const float*)d_in[5];
    const float* b1    = (const float*)d_in[6];
    const float* w2    = (const float*)d_in[7];
    const float* b2    = (const float*)d_in[8];
    const float* gw    = (const float*)d_in[9];
    const float* gas   = (const float*)d_in[10];
    const float* gad   = (const float*)d_in[11];
    const float* gb    = (const float*)d_in[12];
    const float* se1w  = (const float*)d_in[13];
    const float* se1b  = (const float*)d_in[14];
    const float* se2w  = (const float*)d_in[15];
    const float* se2b  = (const float*)d_in[16];
    const float* fc1w  = (const float*)d_in[17];
    const float* fc1b  = (const float*)d_in[18];
    const float* fc2w  = (const float*)d_in[19];
    const float* fc2b  = (const float*)d_in[20];
    const float* fc3w  = (const float*)d_in[21];
    const float* fc3b  = (const float*)d_in[22];
    const float* fc4w  = (const float*)d_in[23];
    const float* fc4b  = (const float*)d_in[24];
    const float* outw  = (const float*)d_in[25];
    const float* outb  = (const float*)d_in[26];
    float* out = (float*)d_out;
    float* ws  = (float*)d_ws;

    const size_t NF = (size_t)NTOT * 128;
    float* xA    = ws;
    float* xB    = xA + NF;
    float* hbuf  = xB + NF;
    float* xsum  = hbuf + NF;
    float* sm    = xsum + NF;
    float* asn   = sm;                     sm += NTOT;
    float* adn   = sm;                     sm += NTOT;
    float* sl    = sm;                     sm += NTOT;
    float* WR1   = sm;                     sm += 79 * SEHID;
    float* WC1   = sm;                     sm += 192 * SEHID;
    float* cmidT = sm;                     sm += 32 * SEHID;
    float* wgt   = sm;                     sm += 32 * SEIN;
    float* part  = sm;                     sm += (size_t)NSPLIT * 32 * SEIN;
    int*   cnt   = (int*)sm;
    int*   eidxc = cnt + NTOT;

    hipMemsetAsync(cnt, 0, NTOT * sizeof(int), stream);

    // K1: node-MLP | WR1 stream | CSR build  (all independent)
    k1<<<716, 256, 0, stream>>>(x1, x2, w1, b1, w2, b2, xA, se1w, WR1, de, pe, cnt, eidxc);

    // K2: GAT-h layer 0 | WC1 stream (se1w L3-resident after K1)
    k2<<<926, 256, 0, stream>>>(xA, gw, gas, gad, hbuf, asn, adn, se1w, WC1);

    gat_gather<<<4336, 256, 0, stream>>>(cnt, eidxc, asn, adn, hbuf,
                                         gb + 0 * 128, gb + 3 * 128,
                                         xB, xsum, sl, 1, 0);
    gath<<<542, 256, 0, stream>>>(xB, gw, gas, gad, 1, hbuf, asn, adn);
    gat_gather<<<4336, 256, 0, stream>>>(cnt, eidxc, asn, adn, hbuf,
                                         gb + 1 * 128, gb + 4 * 128,
                                         xA, xsum, sl, 0, 0);
    gath<<<542, 256, 0, stream>>>(xA, gw, gas, gad, 2, hbuf, asn, adn);
    gat_gather<<<4336, 256, 0, stream>>>(cnt, eidxc, asn, adn, hbuf,
                                         gb + 2 * 128, gb + 5 * 128,
                                         nullptr, xsum, sl, 0, 1);

    se1_small<<<dim3(8, 32), 256, 0, stream>>>(sl, WR1, WC1, se1b, cmidT);
    se2p<<<dim3(15, NSPLIT), 256, 0, stream>>>(cmidT, se2w, part);
    se2fin<<<1896, 256, 0, stream>>>(part, se2b, inter, wgt);
    tail32<<<32, 256, 0, stream>>>(wgt, xsum, fc1w, fc1b, fc2w, fc2b,
                                   fc3w, fc3b, fc4w, fc4b, outw, outb, out);
}